// Round 3
// baseline (750.695 us; speedup 1.0000x reference)
//
#include <hip/hip_runtime.h>
#include <hip/hip_bf16.h>

typedef unsigned short ushort_t;
typedef unsigned int uint_t;

#define BB 512
#define TT 256
#define CC 192
#define HH 64

// ---- bf16 helpers (bit tricks; exact) ----
__device__ __forceinline__ float bflo(uint_t u) {
    union { uint_t i; float f; } v; v.i = u << 16; return v.f;
}
__device__ __forceinline__ float bfhi(uint_t u) {
    union { uint_t i; float f; } v; v.i = u & 0xffff0000u; return v.f;
}
__device__ __forceinline__ ushort_t f2bf(float f) {
    __hip_bfloat16 h = __float2bfloat16(f);   // RNE
    ushort_t u; __builtin_memcpy(&u, &h, 2); return u;
}

// ---- precompute pos_k = pe@Wk, pos_q = pe@Wq (fp32, into ws) ----
__global__ void pos_kernel(const float* __restrict__ Wk,
                           const float* __restrict__ Wq,
                           const float* __restrict__ pe,
                           float* __restrict__ posk, float* __restrict__ posq) {
    int t = blockIdx.x;          // 0..255
    int h = threadIdx.x;         // 0..63
    float ak = 0.f, aq = 0.f;
    for (int c = 0; c < CC; ++c) {
        float xv = pe[t * CC + c];            // wave-uniform -> broadcast
        ak += xv * Wk[c * HH + h];            // coalesced
        aq += xv * Wq[c * HH + h];
    }
    posk[t * HH + h] = ak;
    posq[t * HH + h] = aq;
}

// ---- biasT[j][t] = bias[t][j] = posk[t] . posq[j]  (transposed for coalesced flash reads) ----
__global__ void bias_kernel(const float* __restrict__ posk,
                            const float* __restrict__ posq,
                            float* __restrict__ biasT) {
    int j = blockIdx.x;          // key index
    int t = threadIdx.x;         // query index (coalesced store)
    float s = 0.f;
    #pragma unroll
    for (int h = 0; h < HH; ++h)
        s += posk[t * HH + h] * posq[j * HH + h];
    biasT[j * TT + t] = s;
}

// ---- fused per-batch attention ----
__global__ __launch_bounds__(256, 2)
void attn_kernel(const float* __restrict__ x,
                 const float* __restrict__ Wk,
                 const float* __restrict__ Wq,
                 const float* __restrict__ Wv,
                 const float* __restrict__ biasT,
                 float* __restrict__ out) {
    __shared__ ushort_t k_s[TT * HH];   // 32 KB: k (bf16)
    __shared__ ushort_t a_s[TT * HH];   // 32 KB: q first, then v (bf16)

    const int b   = blockIdx.x;
    const int tid = threadIdx.x;
    const int h   = tid & 63;
    const int wv  = tid >> 6;           // wave id 0..3
    const float* xb = x + (size_t)b * TT * CC;

    // ---- Phase 1: q -> a_s, k -> k_s.  Each wave: 16 rows per 64-row tile. ----
    for (int tile = 0; tile < 4; ++tile) {
        const int r0 = tile * 64 + wv * 16;
        float qa[16], ka[16];
        #pragma unroll
        for (int i = 0; i < 16; ++i) { qa[i] = 0.f; ka[i] = 0.f; }
        for (int cc = 0; cc < CC; cc += 4) {
            float wq4[4], wk4[4];
            #pragma unroll
            for (int u = 0; u < 4; ++u) {
                wq4[u] = Wq[(cc + u) * HH + h];   // coalesced, L1/L2-resident
                wk4[u] = Wk[(cc + u) * HH + h];
            }
            #pragma unroll
            for (int i = 0; i < 16; ++i) {
                // 16B wave-uniform load of 4 fp32 x values (row r0+i, cols cc..cc+3)
                const float4 xv = *reinterpret_cast<const float4*>(xb + (size_t)(r0 + i) * CC + cc);
                qa[i] += xv.x * wq4[0] + xv.y * wq4[1] + xv.z * wq4[2] + xv.w * wq4[3];
                ka[i] += xv.x * wk4[0] + xv.y * wk4[1] + xv.z * wk4[2] + xv.w * wk4[3];
            }
        }
        #pragma unroll
        for (int i = 0; i < 16; ++i) {
            a_s[(r0 + i) * HH + h] = f2bf(qa[i]);
            k_s[(r0 + i) * HH + h] = f2bf(ka[i]);
        }
    }
    __syncthreads();

    // ---- Phase 2: thread t pulls its q row into registers (bf16 -> fp32) ----
    float qreg[64];
    {
        const uint_t* aw = reinterpret_cast<const uint_t*>(a_s) + tid * 32;
        #pragma unroll
        for (int p = 0; p < 32; ++p) {
            uint_t w = aw[p];
            qreg[2 * p]     = bflo(w);
            qreg[2 * p + 1] = bfhi(w);
        }
    }
    __syncthreads();

    // ---- Phase 3: v -> a_s (overwrite q) ----
    for (int tile = 0; tile < 4; ++tile) {
        const int r0 = tile * 64 + wv * 16;
        float va[16];
        #pragma unroll
        for (int i = 0; i < 16; ++i) va[i] = 0.f;
        for (int cc = 0; cc < CC; cc += 4) {
            float wv4[4];
            #pragma unroll
            for (int u = 0; u < 4; ++u)
                wv4[u] = Wv[(cc + u) * HH + h];
            #pragma unroll
            for (int i = 0; i < 16; ++i) {
                const float4 xv = *reinterpret_cast<const float4*>(xb + (size_t)(r0 + i) * CC + cc);
                va[i] += xv.x * wv4[0] + xv.y * wv4[1] + xv.z * wv4[2] + xv.w * wv4[3];
            }
        }
        #pragma unroll
        for (int i = 0; i < 16; ++i)
            a_s[(r0 + i) * HH + h] = f2bf(va[i]);
    }
    __syncthreads();

    // ---- Phase 4: online-max (flash-style) causal softmax-attention, query row t = tid ----
    const int t = tid;
    float acc[64];
    #pragma unroll
    for (int i = 0; i < 64; ++i) acc[i] = 0.f;
    float l = 0.f;
    float m = -1e30f;
    const float scale = 0.07216878364870322f;  // 192^-0.5
    const uint_t* kw = reinterpret_cast<const uint_t*>(k_s);
    const uint_t* vw = reinterpret_cast<const uint_t*>(a_s);

    for (int j = 0; j <= t; ++j) {             // divergent bound: tail lanes masked
        float s = 0.f;
        #pragma unroll
        for (int p = 0; p < 32; ++p) {         // wave-uniform LDS broadcast
            uint_t w = kw[j * 32 + p];
            s += qreg[2 * p] * bflo(w) + qreg[2 * p + 1] * bfhi(w);
        }
        s = s * scale + biasT[j * TT + t];     // coalesced fp32
        if (s > m) {
            float alpha = __expf(m - s);       // first iter: exp(-huge) = 0 -> clean init
            l *= alpha;
            #pragma unroll
            for (int i = 0; i < 64; ++i) acc[i] *= alpha;
            m = s;
        }
        float pj = __expf(s - m);              // in (0,1]
        l += pj;
        #pragma unroll
        for (int p = 0; p < 32; ++p) {
            uint_t w = vw[j * 32 + p];
            acc[2 * p]     += pj * bflo(w);
            acc[2 * p + 1] += pj * bfhi(w);
        }
    }

    const float rl = 1.f / l;                  // l in [1, 256] -> safe
    float* orow = out + ((size_t)b * TT + t) * HH;
    #pragma unroll
    for (int g = 0; g < 16; ++g) {             // 16 x 16B fp32 stores per 256B row
        float4 o;
        o.x = acc[g * 4 + 0] * rl;
        o.y = acc[g * 4 + 1] * rl;
        o.z = acc[g * 4 + 2] * rl;
        o.w = acc[g * 4 + 3] * rl;
        reinterpret_cast<float4*>(orow)[g] = o;
    }
}

extern "C" void kernel_launch(void* const* d_in, const int* in_sizes, int n_in,
                              void* d_out, int out_size, void* d_ws, size_t ws_size,
                              hipStream_t stream) {
    const float* x  = (const float*)d_in[0];
    const float* Wk = (const float*)d_in[1];
    const float* Wq = (const float*)d_in[2];
    const float* Wv = (const float*)d_in[3];
    const float* pe = (const float*)d_in[4];
    float* out = (float*)d_out;

    // ws layout: biasT[256*256] f32 | posk[256*64] f32 | posq[256*64] f32  (384 KB)
    float* biasT = (float*)d_ws;
    float* posk  = biasT + TT * TT;
    float* posq  = posk + TT * HH;

    pos_kernel<<<TT, HH, 0, stream>>>(Wk, Wq, pe, posk, posq);
    bias_kernel<<<TT, TT, 0, stream>>>(posk, posq, biasT);
    attn_kernel<<<BB, 256, 0, stream>>>(x, Wk, Wq, Wv, biasT, out);
}

// Round 4
// 297.606 us; speedup vs baseline: 2.5224x; 2.5224x over previous
//
#include <hip/hip_runtime.h>
#include <hip/hip_bf16.h>

typedef unsigned short u16;
typedef unsigned int u32;
using bf16x8 = __attribute__((ext_vector_type(8))) short;  // 8 bf16 (4 VGPRs)
using f32x4  = __attribute__((ext_vector_type(4))) float;  // 4 fp32

#define BB 512
#define TT 256
#define CC 192
#define HH 64

#define KP 72      // K_s pitch (elems): mult of 8 (16B align), 36 dwords/row -> 2-way banks
#define VP 264     // Vt_s / P pitch: mult of 8, 132 dwords/row -> 2-way banks
#define K_OFF 0            // 256*72  = 18432 elems
#define VT_OFF 18432       // 64*264  = 16896 elems
#define W_OFF  35328       // 4 waves * 4608 elems (Q staging then P buffer)
#define LDS_ELEMS 53760    // 107520 B total (gfx950 LDS = 160 KB/CU)

__device__ __forceinline__ u16 f2bf(float f) {
    __hip_bfloat16 h = __float2bfloat16(f);   // RNE
    u16 u; __builtin_memcpy(&u, &h, 2); return u;
}

// ---- Wt[w][h][c] bf16, w in {q,k,v}: transposed weights for 16B B-frag loads ----
__global__ void wprep_kernel(const float* __restrict__ Wq,
                             const float* __restrict__ Wk,
                             const float* __restrict__ Wv,
                             u16* __restrict__ Wt) {
    int idx = blockIdx.x * 256 + threadIdx.x;       // 0..36863
    int wsel = idx / (HH * CC);
    int rem  = idx % (HH * CC);
    int h = rem / CC, c = rem % CC;
    const float* W = (wsel == 0) ? Wq : (wsel == 1) ? Wk : Wv;
    Wt[idx] = f2bf(W[c * HH + h]);
}

// ---- poskT[h][t], posqT[h][t] (transposed so bias_kernel reads coalesce) ----
__global__ void pos_kernel(const float* __restrict__ Wk,
                           const float* __restrict__ Wq,
                           const float* __restrict__ pe,
                           float* __restrict__ poskT, float* __restrict__ posqT) {
    int t = blockIdx.x;          // 0..255
    int h = threadIdx.x;         // 0..63
    float ak = 0.f, aq = 0.f;
    for (int c = 0; c < CC; ++c) {
        float p = pe[t * CC + c];             // wave-uniform broadcast
        ak += p * Wk[c * HH + h];             // coalesced
        aq += p * Wq[c * HH + h];
    }
    poskT[h * TT + t] = ak;
    posqT[h * TT + t] = aq;
}

// ---- biasT[j][t] = posk[t].posq[j] ----
__global__ void bias_kernel(const float* __restrict__ poskT,
                            const float* __restrict__ posqT,
                            float* __restrict__ biasT) {
    int j = blockIdx.x;          // key index (uniform)
    int t = threadIdx.x;         // query index (coalesced)
    float s = 0.f;
    #pragma unroll
    for (int h = 0; h < HH; ++h)
        s += poskT[h * TT + t] * posqT[h * TT + j];
    biasT[j * TT + t] = s;
}

// ---- fused per-batch MFMA attention ----
// Fragment maps (mfma_f32_16x16x32_bf16, guide-verified):
//   A: lane holds A[m=lane&15][k=(lane>>4)*8+u], u=0..7
//   B: lane holds B[k=(lane>>4)*8+u][n=lane&15]
//   C/D: lane reg r holds D[row=(lane>>4)*4+r][col=lane&15]
__global__ __launch_bounds__(256, 1)
void attn_kernel(const float* __restrict__ x,
                 const u16* __restrict__ Wt,      // [3][64][192] bf16 (q,k,v)
                 const float* __restrict__ biasT, // [j][t] fp32
                 float* __restrict__ out) {
    __shared__ __align__(16) u16 lds[LDS_ELEMS];

    const int tid  = threadIdx.x;
    const int w    = tid >> 6;       // wave 0..3
    const int lane = tid & 63;
    const int l15  = lane & 15;
    const int quad = lane >> 4;
    const int b    = blockIdx.x;
    const float* xb = x + (size_t)b * TT * CC;
    u16* Qw = &lds[W_OFF + w * 4608];   // per-wave scratch: Q staging, then P buffer

    const f32x4 zero4 = {0.f, 0.f, 0.f, 0.f};
    const u16* Wtq = Wt;
    const u16* Wtk = Wt + HH * CC;
    const u16* Wtv = Wt + 2 * HH * CC;

    // ================= Phase 1: QKV projection via MFMA =================
    // wave w owns m-tiles i = w, w+4, w+8, w+12 (16 q-rows each)
    for (int mt = 0; mt < 4; ++mt) {
        const int i  = w + 4 * mt;
        const int t0 = 16 * i;
        f32x4 aq[4], ak[4], av[4];
        #pragma unroll
        for (int n = 0; n < 4; ++n) { aq[n] = zero4; ak[n] = zero4; av[n] = zero4; }
        #pragma unroll
        for (int ks = 0; ks < 6; ++ks) {
            const int c0 = 32 * ks;
            // A-frag: X[t0+l15][c0+quad*8 .. +7] fp32 -> bf16
            const float* xp = xb + (size_t)(t0 + l15) * CC + c0 + quad * 8;
            const float4 x0 = *(const float4*)xp;
            const float4 x1 = *(const float4*)(xp + 4);
            bf16x8 a;
            a[0]=(short)f2bf(x0.x); a[1]=(short)f2bf(x0.y);
            a[2]=(short)f2bf(x0.z); a[3]=(short)f2bf(x0.w);
            a[4]=(short)f2bf(x1.x); a[5]=(short)f2bf(x1.y);
            a[6]=(short)f2bf(x1.z); a[7]=(short)f2bf(x1.w);
            #pragma unroll
            for (int n = 0; n < 4; ++n) {
                const int off = (n * 16 + l15) * CC + c0 + quad * 8;
                bf16x8 bq = *(const bf16x8*)(Wtq + off);
                bf16x8 bk = *(const bf16x8*)(Wtk + off);
                bf16x8 bv = *(const bf16x8*)(Wtv + off);
                aq[n] = __builtin_amdgcn_mfma_f32_16x16x32_bf16(a, bq, aq[n], 0, 0, 0);
                ak[n] = __builtin_amdgcn_mfma_f32_16x16x32_bf16(a, bk, ak[n], 0, 0, 0);
                av[n] = __builtin_amdgcn_mfma_f32_16x16x32_bf16(a, bv, av[n], 0, 0, 0);
            }
        }
        // write K -> K_s[j][h], V -> Vt[h][j], Q -> per-wave scratch
        #pragma unroll
        for (int n = 0; n < 4; ++n)
        #pragma unroll
        for (int r = 0; r < 4; ++r) {
            const int row = t0 + quad * 4 + r;
            const int col = n * 16 + l15;
            lds[K_OFF + row * KP + col] = f2bf(ak[n][r]);
            lds[VT_OFF + col * VP + row] = f2bf(av[n][r]);
            Qw[mt * 1152 + (quad * 4 + r) * KP + col] = f2bf(aq[n][r]);
        }
    }
    __syncthreads();   // K_s/Vt_s are cross-wave

    // ================= Phase 2: Q A-frags -> registers =================
    bf16x8 qf[4][2];
    #pragma unroll
    for (int mt = 0; mt < 4; ++mt)
    #pragma unroll
    for (int hs = 0; hs < 2; ++hs)
        qf[mt][hs] = *(const bf16x8*)&Qw[mt * 1152 + l15 * KP + hs * 32 + quad * 8];

    // ================= Phase 3: flash per m-tile =================
    const float scale = 0.07216878364870322f;  // 192^-0.5
    #pragma unroll 1
    for (int mt = 0; mt < 4; ++mt) {
        const int i  = w + 4 * mt;   // wave-uniform
        const int t0 = 16 * i;
        const int J  = i + 1;        // causal n-tile count

        // ---- S = Q K^T * scale + bias, causal mask ----
        f32x4 sf[16];
        #pragma unroll
        for (int jt = 0; jt < 16; ++jt) {
            if (jt < J) {
                bf16x8 bk0 = *(const bf16x8*)&lds[K_OFF + (jt * 16 + l15) * KP + quad * 8];
                bf16x8 bk1 = *(const bf16x8*)&lds[K_OFF + (jt * 16 + l15) * KP + 32 + quad * 8];
                f32x4 s4 = zero4;
                s4 = __builtin_amdgcn_mfma_f32_16x16x32_bf16(qf[mt][0], bk0, s4, 0, 0, 0);
                s4 = __builtin_amdgcn_mfma_f32_16x16x32_bf16(qf[mt][1], bk1, s4, 0, 0, 0);
                const float4 b4 = *(const float4*)&biasT[(jt * 16 + l15) * TT + t0 + quad * 4];
                s4[0] = s4[0] * scale + b4.x;
                s4[1] = s4[1] * scale + b4.y;
                s4[2] = s4[2] * scale + b4.z;
                s4[3] = s4[3] * scale + b4.w;
                if (jt == i) {  // diagonal tile: mask col > row
                    #pragma unroll
                    for (int r = 0; r < 4; ++r)
                        if (l15 > quad * 4 + r) s4[r] = -1e30f;
                }
                sf[jt] = s4;
            }
        }
        // ---- row max (16-lane groups share a row set) ----
        float m4[4] = {-1e30f, -1e30f, -1e30f, -1e30f};
        #pragma unroll
        for (int jt = 0; jt < 16; ++jt)
            if (jt < J) {
                #pragma unroll
                for (int r = 0; r < 4; ++r) m4[r] = fmaxf(m4[r], sf[jt][r]);
            }
        #pragma unroll
        for (int d = 1; d < 16; d <<= 1) {
            #pragma unroll
            for (int r = 0; r < 4; ++r) m4[r] = fmaxf(m4[r], __shfl_xor(m4[r], d, 64));
        }
        // ---- exp + row sum + P -> per-wave LDS (bf16) ----
        float l4[4] = {0.f, 0.f, 0.f, 0.f};
        #pragma unroll
        for (int jt = 0; jt < 16; ++jt) {
            if (jt < J) {
                #pragma unroll
                for (int r = 0; r < 4; ++r) {
                    float e = __expf(sf[jt][r] - m4[r]);
                    l4[r] += e;
                    Qw[(quad * 4 + r) * VP + jt * 16 + l15] = f2bf(e);
                }
            }
        }
        if (J & 1) {  // zero the pad tile so the last K=32 PV step is clean
            #pragma unroll
            for (int r = 0; r < 4; ++r)
                Qw[(quad * 4 + r) * VP + J * 16 + l15] = 0;
        }
        #pragma unroll
        for (int d = 1; d < 16; d <<= 1) {
            #pragma unroll
            for (int r = 0; r < 4; ++r) l4[r] += __shfl_xor(l4[r], d, 64);
        }
        // ---- O = P V ----
        const int KS = (J + 1) >> 1;
        f32x4 o[4] = {zero4, zero4, zero4, zero4};
        #pragma unroll
        for (int ks = 0; ks < 8; ++ks) {
            if (ks < KS) {
                bf16x8 pa = *(const bf16x8*)&Qw[l15 * VP + ks * 32 + quad * 8];
                #pragma unroll
                for (int n = 0; n < 4; ++n) {
                    bf16x8 bv = *(const bf16x8*)&lds[VT_OFF + (n * 16 + l15) * VP + ks * 32 + quad * 8];
                    o[n] = __builtin_amdgcn_mfma_f32_16x16x32_bf16(pa, bv, o[n], 0, 0, 0);
                }
            }
        }
        // ---- normalize + store ----
        float rl4[4];
        #pragma unroll
        for (int r = 0; r < 4; ++r) rl4[r] = 1.f / l4[r];
        float* ob = out + ((size_t)b * TT + t0) * HH;
        #pragma unroll
        for (int n = 0; n < 4; ++n)
        #pragma unroll
        for (int r = 0; r < 4; ++r)
            ob[(quad * 4 + r) * HH + n * 16 + l15] = o[n][r] * rl4[r];
    }
}

extern "C" void kernel_launch(void* const* d_in, const int* in_sizes, int n_in,
                              void* d_out, int out_size, void* d_ws, size_t ws_size,
                              hipStream_t stream) {
    const float* x  = (const float*)d_in[0];
    const float* Wk = (const float*)d_in[1];
    const float* Wq = (const float*)d_in[2];
    const float* Wv = (const float*)d_in[3];
    const float* pe = (const float*)d_in[4];
    float* out = (float*)d_out;

    // ws: biasT[65536]f | poskT[16384]f | posqT[16384]f | Wt[36864]bf16  (~457 KB)
    float* biasT = (float*)d_ws;
    float* poskT = biasT + TT * TT;
    float* posqT = poskT + TT * HH;
    u16*   Wt    = (u16*)(posqT + TT * HH);

    wprep_kernel<<<(3 * HH * CC) / 256, 256, 0, stream>>>(Wq, Wk, Wv, Wt);
    pos_kernel<<<TT, HH, 0, stream>>>(Wk, Wq, pe, poskT, posqT);
    bias_kernel<<<TT, TT, 0, stream>>>(poskT, posqT, biasT);
    attn_kernel<<<BB, 256, 0, stream>>>(x, Wt, biasT, out);
}

// Round 5
// 275.535 us; speedup vs baseline: 2.7245x; 1.0801x over previous
//
#include <hip/hip_runtime.h>
#include <hip/hip_bf16.h>

typedef unsigned short u16;
typedef unsigned int u32;
using bf16x8 = __attribute__((ext_vector_type(8))) short;  // 8 bf16 (4 VGPRs)
using f32x4  = __attribute__((ext_vector_type(4))) float;  // 4 fp32

#define BB 512
#define TT 256
#define CC 192
#define HH 64

__device__ __forceinline__ u16 f2bf(float f) {
    __hip_bfloat16 h = __float2bfloat16(f);   // RNE
    u16 u; __builtin_memcpy(&u, &h, 2); return u;
}

// ================= prep kernels (shared by both paths) =================

// Wt3[h3][c] bf16, h3 = matrix*64 + h, matrix in {q,k,v}
__global__ void wprep_kernel(const float* __restrict__ Wq,
                             const float* __restrict__ Wk,
                             const float* __restrict__ Wv,
                             u16* __restrict__ Wt) {
    int idx = blockIdx.x * 256 + threadIdx.x;       // 0..36863
    int wsel = idx / (HH * CC);
    int rem  = idx % (HH * CC);
    int h = rem / CC, c = rem % CC;
    const float* W = (wsel == 0) ? Wq : (wsel == 1) ? Wk : Wv;
    Wt[idx] = f2bf(W[c * HH + h]);
}

// poskT[h][t], posqT[h][t]
__global__ void pos_kernel(const float* __restrict__ Wk,
                           const float* __restrict__ Wq,
                           const float* __restrict__ pe,
                           float* __restrict__ poskT, float* __restrict__ posqT) {
    int t = blockIdx.x * 4 + (threadIdx.x >> 6);   // grid 64 x 256
    int h = threadIdx.x & 63;
    float ak = 0.f, aq = 0.f;
    for (int c = 0; c < CC; ++c) {
        float p = pe[t * CC + c];             // group-uniform broadcast
        ak += p * Wk[c * HH + h];             // coalesced
        aq += p * Wq[c * HH + h];
    }
    poskT[h * TT + t] = ak;
    posqT[h * TT + t] = aq;
}

// biasT[j][t] = posk[t].posq[j]
__global__ void bias_kernel(const float* __restrict__ poskT,
                            const float* __restrict__ posqT,
                            float* __restrict__ biasT) {
    int j = blockIdx.x;          // key index (uniform)
    int t = threadIdx.x;         // query index (coalesced)
    float s = 0.f;
    #pragma unroll
    for (int h = 0; h < HH; ++h)
        s += poskT[h * TT + t] * posqT[h * TT + j];
    biasT[j * TT + t] = s;
}

// ================= Path A kernel 1: QKV projection GEMM =================
// grid 2048 x 256: global wave g owns batch b = g>>4, m-tile t0 = (g&15)*16.
// No LDS, ~110 VGPR -> high occupancy.
__global__ __launch_bounds__(256, 4)
void qkv_kernel(const float* __restrict__ x,
                const u16* __restrict__ Wt3,    // [192 h3][192 c] bf16
                u16* __restrict__ qg, u16* __restrict__ kg, u16* __restrict__ vg) {
    const int tid  = threadIdx.x;
    const int g    = blockIdx.x * 4 + (tid >> 6);
    const int lane = tid & 63;
    const int l15  = lane & 15;
    const int quad = lane >> 4;
    const int b    = g >> 4;
    const int t0   = (g & 15) * 16;

    f32x4 acc[12];
    #pragma unroll
    for (int n = 0; n < 12; ++n) acc[n] = {0.f, 0.f, 0.f, 0.f};

    #pragma unroll
    for (int ks = 0; ks < 6; ++ks) {
        const int c0 = ks * 32;
        const float* xp = x + ((size_t)b * TT + t0 + l15) * CC + c0 + quad * 8;
        const float4 x0 = *(const float4*)xp;
        const float4 x1 = *(const float4*)(xp + 4);
        bf16x8 a;
        a[0]=(short)f2bf(x0.x); a[1]=(short)f2bf(x0.y);
        a[2]=(short)f2bf(x0.z); a[3]=(short)f2bf(x0.w);
        a[4]=(short)f2bf(x1.x); a[5]=(short)f2bf(x1.y);
        a[6]=(short)f2bf(x1.z); a[7]=(short)f2bf(x1.w);
        #pragma unroll
        for (int n = 0; n < 12; ++n) {
            bf16x8 bw = *(const bf16x8*)(Wt3 + (n * 16 + l15) * CC + c0 + quad * 8);
            acc[n] = __builtin_amdgcn_mfma_f32_16x16x32_bf16(a, bw, acc[n], 0, 0, 0);
        }
    }
    #pragma unroll
    for (int n = 0; n < 12; ++n) {
        u16* dst = (n < 4) ? qg : (n < 8) ? kg : vg;
        const int hcol = (n & 3) * 16 + l15;
        #pragma unroll
        for (int r = 0; r < 4; ++r)
            dst[((size_t)b * TT + t0 + quad * 4 + r) * HH + hcol] = f2bf(acc[n][r]);
    }
}

// ================= Path A kernel 2: lean flash attention =================
// LDS: Vt[64][264] + per-wave P[16][40]  = 38,912 B -> 4 blocks/CU.
// grid 1024 (2 blocks/batch); wave tile sets balanced to SumJ = 17 each.
#define VP 264
#define PP 40
#define VT_ELEMS (HH * VP)               // 16896
#define P_ELEMS 640                      // 16*40
#define LDSB_ELEMS (VT_ELEMS + 4 * P_ELEMS)

__global__ __launch_bounds__(256, 4)
void attn_kernel(const u16* __restrict__ qg, const u16* __restrict__ kg,
                 const u16* __restrict__ vg, const float* __restrict__ biasT,
                 float* __restrict__ out) {
    __shared__ __align__(16) u16 lds[LDSB_ELEMS];
    const int tid  = threadIdx.x;
    const int w    = tid >> 6;
    const int lane = tid & 63;
    const int l15  = lane & 15;
    const int quad = lane >> 4;
    const int b    = blockIdx.x >> 1;
    const int half = blockIdx.x & 1;

    // ---- stage V^T: thread tid handles key-row j = tid ----
    {
        const u16* vrow = vg + ((size_t)b * TT + tid) * HH;
        #pragma unroll
        for (int u = 0; u < 8; ++u) {
            bf16x8 vv = *(const bf16x8*)(vrow + u * 8);
            #pragma unroll
            for (int e = 0; e < 8; ++e)
                lds[(u * 8 + e) * VP + tid] = (u16)vv[e];
        }
    }
    __syncthreads();

    u16* Pw = &lds[VT_ELEMS + w * P_ELEMS];
    const float scale = 0.07216878364870322f;  // 192^-0.5
    const f32x4 zero4 = {0.f, 0.f, 0.f, 0.f};

    #pragma unroll 1
    for (int mt = 0; mt < 2; ++mt) {
        // balanced causal tile sets: half0 w: {w, 15-w}; half1 w: {4+w, 11-w}
        const int i  = half ? (mt ? 11 - w : 4 + w) : (mt ? 15 - w : w);
        const int t0 = 16 * i;
        const int J  = i + 1;
        const int Pq = (J + 1) >> 1;

        const u16* qp = qg + ((size_t)b * TT + t0 + l15) * HH + quad * 8;
        const bf16x8 qf0 = *(const bf16x8*)qp;
        const bf16x8 qf1 = *(const bf16x8*)(qp + 32);

        f32x4 o[4];
        float m4[4], l4[4];
        #pragma unroll
        for (int n = 0; n < 4; ++n) o[n] = zero4;
        #pragma unroll
        for (int r = 0; r < 4; ++r) { m4[r] = -1e30f; l4[r] = 0.f; }

        #pragma unroll
        for (int p = 0; p < 8; ++p) {
            if (p < Pq) {
                const int jt0 = 2 * p, jt1 = 2 * p + 1;
                // ---- S tiles (pair) ----
                f32x4 sa = zero4, sb;
                {
                    const u16* kp = kg + ((size_t)b * TT + jt0 * 16 + l15) * HH + quad * 8;
                    bf16x8 k0 = *(const bf16x8*)kp;
                    bf16x8 k1 = *(const bf16x8*)(kp + 32);
                    sa = __builtin_amdgcn_mfma_f32_16x16x32_bf16(qf0, k0, sa, 0, 0, 0);
                    sa = __builtin_amdgcn_mfma_f32_16x16x32_bf16(qf1, k1, sa, 0, 0, 0);
                    const float4 b4 = *(const float4*)&biasT[(jt0 * 16 + l15) * TT + t0 + quad * 4];
                    sa[0] = sa[0] * scale + b4.x;
                    sa[1] = sa[1] * scale + b4.y;
                    sa[2] = sa[2] * scale + b4.z;
                    sa[3] = sa[3] * scale + b4.w;
                    if (jt0 == i) {
                        #pragma unroll
                        for (int r = 0; r < 4; ++r)
                            if (l15 > quad * 4 + r) sa[r] = -1e30f;
                    }
                }
                if (jt1 < J) {
                    sb = zero4;
                    const u16* kp = kg + ((size_t)b * TT + jt1 * 16 + l15) * HH + quad * 8;
                    bf16x8 k0 = *(const bf16x8*)kp;
                    bf16x8 k1 = *(const bf16x8*)(kp + 32);
                    sb = __builtin_amdgcn_mfma_f32_16x16x32_bf16(qf0, k0, sb, 0, 0, 0);
                    sb = __builtin_amdgcn_mfma_f32_16x16x32_bf16(qf1, k1, sb, 0, 0, 0);
                    const float4 b4 = *(const float4*)&biasT[(jt1 * 16 + l15) * TT + t0 + quad * 4];
                    sb[0] = sb[0] * scale + b4.x;
                    sb[1] = sb[1] * scale + b4.y;
                    sb[2] = sb[2] * scale + b4.z;
                    sb[3] = sb[3] * scale + b4.w;
                    if (jt1 == i) {
                        #pragma unroll
                        for (int r = 0; r < 4; ++r)
                            if (l15 > quad * 4 + r) sb[r] = -1e30f;
                    }
                } else {
                    sb[0] = -1e30f; sb[1] = -1e30f; sb[2] = -1e30f; sb[3] = -1e30f;
                }
                // ---- pair row max (16-lane group shares rows) ----
                float t4[4];
                #pragma unroll
                for (int r = 0; r < 4; ++r) t4[r] = fmaxf(sa[r], sb[r]);
                #pragma unroll
                for (int d = 1; d < 16; d <<= 1) {
                    #pragma unroll
                    for (int r = 0; r < 4; ++r) t4[r] = fmaxf(t4[r], __shfl_xor(t4[r], d, 64));
                }
                // ---- online rescale ----
                float al[4];
                #pragma unroll
                for (int r = 0; r < 4; ++r) {
                    float mn = fmaxf(m4[r], t4[r]);
                    al[r] = __expf(m4[r] - mn);   // first pair: exp(-huge)=0
                    m4[r] = mn;
                    l4[r] *= al[r];
                }
                #pragma unroll
                for (int n = 0; n < 4; ++n)
                #pragma unroll
                for (int r = 0; r < 4; ++r) o[n][r] *= al[r];
                // ---- exp + P -> per-wave LDS ----
                #pragma unroll
                for (int r = 0; r < 4; ++r) {
                    float e0 = __expf(sa[r] - m4[r]);
                    float e1 = __expf(sb[r] - m4[r]);   // invalid tile -> exp(-huge)=0
                    l4[r] += e0 + e1;                   // per-lane partial, reduced later
                    Pw[(quad * 4 + r) * PP + l15]      = f2bf(e0);
                    Pw[(quad * 4 + r) * PP + 16 + l15] = f2bf(e1);
                }
                // ---- PV ----
                bf16x8 pa = *(const bf16x8*)&Pw[l15 * PP + quad * 8];
                #pragma unroll
                for (int n = 0; n < 4; ++n) {
                    bf16x8 bv = *(const bf16x8*)&lds[(n * 16 + l15) * VP + p * 32 + quad * 8];
                    o[n] = __builtin_amdgcn_mfma_f32_16x16x32_bf16(pa, bv, o[n], 0, 0, 0);
                }
            }
        }
        // ---- row-sum reduce + normalize + store ----
        #pragma unroll
        for (int d = 1; d < 16; d <<= 1) {
            #pragma unroll
            for (int r = 0; r < 4; ++r) l4[r] += __shfl_xor(l4[r], d, 64);
        }
        float rl4[4];
        #pragma unroll
        for (int r = 0; r < 4; ++r) rl4[r] = 1.f / l4[r];
        float* ob = out + ((size_t)b * TT + t0) * HH;
        #pragma unroll
        for (int n = 0; n < 4; ++n)
        #pragma unroll
        for (int r = 0; r < 4; ++r)
            ob[(quad * 4 + r) * HH + n * 16 + l15] = o[n][r] * rl4[r];
    }
}

// ================= Path B fallback: round-4 monolithic (verified) =================
#define KP 72
#define MVP 264
#define K_OFF 0
#define VT_OFF 18432
#define W_OFF  35328
#define LDS_ELEMS 53760

__global__ __launch_bounds__(256, 1)
void attn_mono(const float* __restrict__ x,
               const u16* __restrict__ Wt,
               const float* __restrict__ biasT,
               float* __restrict__ out) {
    __shared__ __align__(16) u16 lds[LDS_ELEMS];
    const int tid  = threadIdx.x;
    const int w    = tid >> 6;
    const int lane = tid & 63;
    const int l15  = lane & 15;
    const int quad = lane >> 4;
    const int b    = blockIdx.x;
    const float* xb = x + (size_t)b * TT * CC;
    u16* Qw = &lds[W_OFF + w * 4608];
    const f32x4 zero4 = {0.f, 0.f, 0.f, 0.f};
    const u16* Wtq = Wt;
    const u16* Wtk = Wt + HH * CC;
    const u16* Wtv = Wt + 2 * HH * CC;

    for (int mt = 0; mt < 4; ++mt) {
        const int i  = w + 4 * mt;
        const int t0 = 16 * i;
        f32x4 aq[4], ak[4], av[4];
        #pragma unroll
        for (int n = 0; n < 4; ++n) { aq[n] = zero4; ak[n] = zero4; av[n] = zero4; }
        #pragma unroll
        for (int ks = 0; ks < 6; ++ks) {
            const int c0 = 32 * ks;
            const float* xp = xb + (size_t)(t0 + l15) * CC + c0 + quad * 8;
            const float4 x0 = *(const float4*)xp;
            const float4 x1 = *(const float4*)(xp + 4);
            bf16x8 a;
            a[0]=(short)f2bf(x0.x); a[1]=(short)f2bf(x0.y);
            a[2]=(short)f2bf(x0.z); a[3]=(short)f2bf(x0.w);
            a[4]=(short)f2bf(x1.x); a[5]=(short)f2bf(x1.y);
            a[6]=(short)f2bf(x1.z); a[7]=(short)f2bf(x1.w);
            #pragma unroll
            for (int n = 0; n < 4; ++n) {
                const int off = (n * 16 + l15) * CC + c0 + quad * 8;
                bf16x8 bq = *(const bf16x8*)(Wtq + off);
                bf16x8 bk = *(const bf16x8*)(Wtk + off);
                bf16x8 bv = *(const bf16x8*)(Wtv + off);
                aq[n] = __builtin_amdgcn_mfma_f32_16x16x32_bf16(a, bq, aq[n], 0, 0, 0);
                ak[n] = __builtin_amdgcn_mfma_f32_16x16x32_bf16(a, bk, ak[n], 0, 0, 0);
                av[n] = __builtin_amdgcn_mfma_f32_16x16x32_bf16(a, bv, av[n], 0, 0, 0);
            }
        }
        #pragma unroll
        for (int n = 0; n < 4; ++n)
        #pragma unroll
        for (int r = 0; r < 4; ++r) {
            const int row = t0 + quad * 4 + r;
            const int col = n * 16 + l15;
            lds[K_OFF + row * KP + col] = f2bf(ak[n][r]);
            lds[VT_OFF + col * MVP + row] = f2bf(av[n][r]);
            Qw[mt * 1152 + (quad * 4 + r) * KP + col] = f2bf(aq[n][r]);
        }
    }
    __syncthreads();

    bf16x8 qf[4][2];
    #pragma unroll
    for (int mt = 0; mt < 4; ++mt)
    #pragma unroll
    for (int hs = 0; hs < 2; ++hs)
        qf[mt][hs] = *(const bf16x8*)&Qw[mt * 1152 + l15 * KP + hs * 32 + quad * 8];

    const float scale = 0.07216878364870322f;
    #pragma unroll 1
    for (int mt = 0; mt < 4; ++mt) {
        const int i  = w + 4 * mt;
        const int t0 = 16 * i;
        const int J  = i + 1;
        f32x4 sf[16];
        #pragma unroll
        for (int jt = 0; jt < 16; ++jt) {
            if (jt < J) {
                bf16x8 bk0 = *(const bf16x8*)&lds[K_OFF + (jt * 16 + l15) * KP + quad * 8];
                bf16x8 bk1 = *(const bf16x8*)&lds[K_OFF + (jt * 16 + l15) * KP + 32 + quad * 8];
                f32x4 s4 = zero4;
                s4 = __builtin_amdgcn_mfma_f32_16x16x32_bf16(qf[mt][0], bk0, s4, 0, 0, 0);
                s4 = __builtin_amdgcn_mfma_f32_16x16x32_bf16(qf[mt][1], bk1, s4, 0, 0, 0);
                const float4 b4 = *(const float4*)&biasT[(jt * 16 + l15) * TT + t0 + quad * 4];
                s4[0] = s4[0] * scale + b4.x;
                s4[1] = s4[1] * scale + b4.y;
                s4[2] = s4[2] * scale + b4.z;
                s4[3] = s4[3] * scale + b4.w;
                if (jt == i) {
                    #pragma unroll
                    for (int r = 0; r < 4; ++r)
                        if (l15 > quad * 4 + r) s4[r] = -1e30f;
                }
                sf[jt] = s4;
            }
        }
        float m4[4] = {-1e30f, -1e30f, -1e30f, -1e30f};
        #pragma unroll
        for (int jt = 0; jt < 16; ++jt)
            if (jt < J) {
                #pragma unroll
                for (int r = 0; r < 4; ++r) m4[r] = fmaxf(m4[r], sf[jt][r]);
            }
        #pragma unroll
        for (int d = 1; d < 16; d <<= 1) {
            #pragma unroll
            for (int r = 0; r < 4; ++r) m4[r] = fmaxf(m4[r], __shfl_xor(m4[r], d, 64));
        }
        float l4[4] = {0.f, 0.f, 0.f, 0.f};
        #pragma unroll
        for (int jt = 0; jt < 16; ++jt) {
            if (jt < J) {
                #pragma unroll
                for (int r = 0; r < 4; ++r) {
                    float e = __expf(sf[jt][r] - m4[r]);
                    l4[r] += e;
                    Qw[(quad * 4 + r) * MVP + jt * 16 + l15] = f2bf(e);
                }
            }
        }
        if (J & 1) {
            #pragma unroll
            for (int r = 0; r < 4; ++r)
                Qw[(quad * 4 + r) * MVP + J * 16 + l15] = 0;
        }
        #pragma unroll
        for (int d = 1; d < 16; d <<= 1) {
            #pragma unroll
            for (int r = 0; r < 4; ++r) l4[r] += __shfl_xor(l4[r], d, 64);
        }
        const int KS = (J + 1) >> 1;
        f32x4 o[4] = {zero4, zero4, zero4, zero4};
        #pragma unroll
        for (int ks = 0; ks < 8; ++ks) {
            if (ks < KS) {
                bf16x8 pa = *(const bf16x8*)&Qw[l15 * MVP + ks * 32 + quad * 8];
                #pragma unroll
                for (int n = 0; n < 4; ++n) {
                    bf16x8 bv = *(const bf16x8*)&lds[VT_OFF + (n * 16 + l15) * MVP + ks * 32 + quad * 8];
                    o[n] = __builtin_amdgcn_mfma_f32_16x16x32_bf16(pa, bv, o[n], 0, 0, 0);
                }
            }
        }
        float rl4[4];
        #pragma unroll
        for (int r = 0; r < 4; ++r) rl4[r] = 1.f / l4[r];
        float* ob = out + ((size_t)b * TT + t0) * HH;
        #pragma unroll
        for (int n = 0; n < 4; ++n)
        #pragma unroll
        for (int r = 0; r < 4; ++r)
            ob[(quad * 4 + r) * HH + n * 16 + l15] = o[n][r] * rl4[r];
    }
}

extern "C" void kernel_launch(void* const* d_in, const int* in_sizes, int n_in,
                              void* d_out, int out_size, void* d_ws, size_t ws_size,
                              hipStream_t stream) {
    const float* x  = (const float*)d_in[0];
    const float* Wk = (const float*)d_in[1];
    const float* Wq = (const float*)d_in[2];
    const float* Wv = (const float*)d_in[3];
    const float* pe = (const float*)d_in[4];
    float* out = (float*)d_out;

    // ws: biasT[65536]f | poskT[16384]f | posqT[16384]f | Wt3[36864]u16 | q|k|v bf16
    float* biasT = (float*)d_ws;
    float* poskT = biasT + TT * TT;
    float* posqT = poskT + TT * HH;
    u16*   Wt3   = (u16*)(posqT + TT * HH);
    u16*   qg    = Wt3 + 3 * HH * CC;
    u16*   kg    = qg + (size_t)BB * TT * HH;
    u16*   vg    = kg + (size_t)BB * TT * HH;
    const size_t need = (size_t)(466944) + 3ull * BB * TT * HH * 2;  // ~50.8 MB

    wprep_kernel<<<(3 * HH * CC) / 256, 256, 0, stream>>>(Wq, Wk, Wv, Wt3);
    pos_kernel<<<TT / 4, 256, 0, stream>>>(Wk, Wq, pe, poskT, posqT);
    bias_kernel<<<TT, TT, 0, stream>>>(poskT, posqT, biasT);
    if (ws_size >= need) {
        qkv_kernel<<<2048, 256, 0, stream>>>(x, Wt3, qg, kg, vg);
        attn_kernel<<<2 * BB, 256, 0, stream>>>(qg, kg, vg, biasT, out);
    } else {
        attn_mono<<<BB, 256, 0, stream>>>(x, Wt3, biasT, out);
    }
}

// Round 6
// 241.922 us; speedup vs baseline: 3.1031x; 1.1389x over previous
//
#include <hip/hip_runtime.h>
#include <hip/hip_bf16.h>

typedef unsigned short u16;
typedef unsigned int u32;
using bf16x8 = __attribute__((ext_vector_type(8))) short;  // 8 bf16 (4 VGPRs)
using f32x4  = __attribute__((ext_vector_type(4))) float;  // 4 fp32

#define BB 512
#define TT 256
#define CC 192
#define HH 64

__device__ __forceinline__ u16 f2bf(float f) {
    __hip_bfloat16 h = __float2bfloat16(f);   // RNE
    u16 u; __builtin_memcpy(&u, &h, 2); return u;
}

// ================= prep kernels =================

// W_sw: B-fragment-swizzled weights. Frag fid = n3*6+ks (n3 = mat*4 + ntile, ks = K-step).
// lane (quad,l15) element u  =  W[c = ks*32+quad*8+u][h = (n3&3)*16+l15] of matrix n3>>2.
__global__ void wprep_kernel(const float* __restrict__ Wq,
                             const float* __restrict__ Wk,
                             const float* __restrict__ Wv,
                             u16* __restrict__ W_sw) {
    int gid  = blockIdx.x * 256 + threadIdx.x;   // 0..4607 (72 frags * 64 lanes)
    int fid  = gid >> 6, lane = gid & 63;
    int n3   = fid / 6,  ks   = fid % 6;
    int l15  = lane & 15, quad = lane >> 4;
    const float* W = (n3 < 4) ? Wq : (n3 < 8) ? Wk : Wv;
    const int h = (n3 & 3) * 16 + l15;
    u16* dst = W_sw + (size_t)gid * 8;
    #pragma unroll
    for (int u = 0; u < 8; ++u) {
        int c = ks * 32 + quad * 8 + u;
        dst[u] = f2bf(W[c * HH + h]);
    }
}

// poskT[h][t], posqT[h][t]
__global__ void pos_kernel(const float* __restrict__ Wk,
                           const float* __restrict__ Wq,
                           const float* __restrict__ pe,
                           float* __restrict__ poskT, float* __restrict__ posqT) {
    int t = blockIdx.x * 4 + (threadIdx.x >> 6);   // grid 64 x 256
    int h = threadIdx.x & 63;
    float ak = 0.f, aq = 0.f;
    for (int c = 0; c < CC; ++c) {
        float p = pe[t * CC + c];             // group-uniform broadcast
        ak += p * Wk[c * HH + h];             // coalesced
        aq += p * Wq[c * HH + h];
    }
    poskT[h * TT + t] = ak;
    posqT[h * TT + t] = aq;
}

// bias in C/D-fragment layout: bias_sw[(i*16+jt)*64 + lane] = float4 over r,
// component r = bias[row t0+quad*4+r][col jt*16+l15]  (only jt<=i written/read)
__global__ void bias_kernel(const float* __restrict__ poskT,
                            const float* __restrict__ posqT,
                            float4* __restrict__ bias_sw) {
    const int i = blockIdx.x >> 4, jt = blockIdx.x & 15;
    if (jt > i) return;
    const int lane = threadIdx.x;
    const int l15 = lane & 15, quad = lane >> 4;
    const int tq = i * 16 + quad * 4;     // query rows tq..tq+3
    const int jc = jt * 16 + l15;         // key col
    float s[4] = {0.f, 0.f, 0.f, 0.f};
    for (int h = 0; h < HH; ++h) {
        float pq = posqT[h * TT + jc];
        #pragma unroll
        for (int r = 0; r < 4; ++r)
            s[r] += poskT[h * TT + tq + r] * pq;
    }
    bias_sw[blockIdx.x * 64 + lane] = make_float4(s[0], s[1], s[2], s[3]);
}

// ================= kernel 1: QKV projection GEMM (coalesced) =================
// grid 2048: block = (b = blk>>2, rb = blk&3) covers rows rb*64..+63 of batch b.
// X staged to LDS via fully-coalesced float4 loads; W frags are coalesced 1KB loads.
#define XP 200   // LDS X pitch (elems); mult of 8 for 16B-aligned ds_read_b128

__global__ __launch_bounds__(256, 4)
void qkv_kernel(const float* __restrict__ x,
                const u16* __restrict__ W_sw,
                u16* __restrict__ q_sw, u16* __restrict__ k_sw,
                u16* __restrict__ vg) {
    __shared__ __align__(16) u16 xs[64 * XP];   // 25,600 B
    const int tid  = threadIdx.x;
    const int w    = tid >> 6;
    const int lane = tid & 63;
    const int l15  = lane & 15;
    const int quad = lane >> 4;
    const int b    = blockIdx.x >> 2;
    const int rb   = blockIdx.x & 3;
    const float* xb = x + ((size_t)b * TT + rb * 64) * CC;   // 64 contiguous rows

    // ---- stage X -> LDS bf16 (coalesced: adjacent tids read adjacent float4) ----
    #pragma unroll
    for (int it = 0; it < 12; ++it) {
        const int flat = (it * 256 + tid) * 4;       // 0..12287
        const int row = flat / CC, col = flat % CC;
        const float4 v = *(const float4*)(xb + flat);
        uint2 pk;
        pk.x = (u32)f2bf(v.x) | ((u32)f2bf(v.y) << 16);
        pk.y = (u32)f2bf(v.z) | ((u32)f2bf(v.w) << 16);
        *(uint2*)&xs[row * XP + col] = pk;
    }
    __syncthreads();

    // ---- MFMA: wave w computes m-tile (16 rows), 12 n-tiles ----
    const bf16x8* Wv8 = (const bf16x8*)W_sw;
    f32x4 acc[12];
    #pragma unroll
    for (int n = 0; n < 12; ++n) acc[n] = {0.f, 0.f, 0.f, 0.f};
    #pragma unroll
    for (int ks = 0; ks < 6; ++ks) {
        const bf16x8 a = *(const bf16x8*)&xs[(w * 16 + l15) * XP + ks * 32 + quad * 8];
        #pragma unroll
        for (int n = 0; n < 12; ++n)
            acc[n] = __builtin_amdgcn_mfma_f32_16x16x32_bf16(a, Wv8[(n * 6 + ks) * 64 + lane], acc[n], 0, 0, 0);
    }

    // ---- epilogue ----
    const int i_loc  = rb * 4 + w;                 // t-tile within batch (0..15)
    const size_t bi  = (size_t)b * 16 + i_loc;
    const int u   = l15 & 7;
    #pragma unroll
    for (int n = 0; n < 4; ++n) {
        const int hs    = n >> 1;
        const int quadp = (n * 2 + (l15 >> 3)) & 3;
        const size_t base = (bi * 2 + hs) * 512 + (quadp * 16 + quad * 4) * 8 + u;
        #pragma unroll
        for (int r = 0; r < 4; ++r) {
            q_sw[base + r * 8] = f2bf(acc[n][r]);      // Q -> A-frag layout
            k_sw[base + r * 8] = f2bf(acc[4 + n][r]);  // K -> B-frag layout
        }
    }
    const size_t t_glob = (size_t)b * TT + i_loc * 16;
    #pragma unroll
    for (int n = 0; n < 4; ++n)
    #pragma unroll
    for (int r = 0; r < 4; ++r)
        vg[(t_glob + quad * 4 + r) * HH + n * 16 + l15] = f2bf(acc[8 + n][r]);
}

// ================= kernel 2: lean flash attention =================
// LDS: Vt[64][264] + per-wave P[16][40] = 38,912 B -> 4 blocks/CU.
// grid 1024 (2 blocks/batch); wave tile sets balanced to SumJ = 17 each.
#define VP 264
#define PP 40
#define VT_ELEMS (HH * VP)               // 16896
#define P_ELEMS 640                      // 16*40
#define LDSB_ELEMS (VT_ELEMS + 4 * P_ELEMS)

__global__ __launch_bounds__(256, 4)
void attn_kernel(const u16* __restrict__ q_sw, const u16* __restrict__ k_sw,
                 const u16* __restrict__ vg, const float4* __restrict__ bias_sw,
                 float* __restrict__ out) {
    __shared__ __align__(16) u16 lds[LDSB_ELEMS];
    const int tid  = threadIdx.x;
    const int w    = tid >> 6;
    const int lane = tid & 63;
    const int l15  = lane & 15;
    const int quad = lane >> 4;
    const int b    = blockIdx.x >> 1;
    const int half = blockIdx.x & 1;

    // ---- stage V^T: thread tid handles key-row j = tid ----
    {
        const u16* vrow = vg + ((size_t)b * TT + tid) * HH;
        #pragma unroll
        for (int u2 = 0; u2 < 8; ++u2) {
            bf16x8 vv = *(const bf16x8*)(vrow + u2 * 8);
            #pragma unroll
            for (int e = 0; e < 8; ++e)
                lds[(u2 * 8 + e) * VP + tid] = (u16)vv[e];
        }
    }
    __syncthreads();

    u16* Pw = &lds[VT_ELEMS + w * P_ELEMS];
    const float scale = 0.07216878364870322f;  // 192^-0.5
    const f32x4 zero4 = {0.f, 0.f, 0.f, 0.f};
    const bf16x8* qv = (const bf16x8*)q_sw;
    const bf16x8* kv = (const bf16x8*)k_sw;

    #pragma unroll 1
    for (int mt = 0; mt < 2; ++mt) {
        // balanced causal tile sets: half0 w: {w, 15-w}; half1 w: {4+w, 11-w}
        const int i  = half ? (mt ? 11 - w : 4 + w) : (mt ? 15 - w : w);
        const int t0 = 16 * i;
        const int J  = i + 1;
        const int Pq = (J + 1) >> 1;
        const size_t bi = (size_t)b * 16 + i;

        const bf16x8 qf0 = qv[(bi * 2 + 0) * 64 + lane];   // coalesced 1KB
        const bf16x8 qf1 = qv[(bi * 2 + 1) * 64 + lane];

        f32x4 o[4];
        float m4[4], l4[4];
        #pragma unroll
        for (int n = 0; n < 4; ++n) o[n] = zero4;
        #pragma unroll
        for (int r = 0; r < 4; ++r) { m4[r] = -1e30f; l4[r] = 0.f; }

        #pragma unroll
        for (int p = 0; p < 8; ++p) {
            if (p < Pq) {
                const int jt0 = 2 * p, jt1 = 2 * p + 1;
                // ---- S tiles (pair), all loads coalesced ----
                f32x4 sa = zero4, sb;
                {
                    const size_t bj = (size_t)b * 16 + jt0;
                    bf16x8 k0 = kv[(bj * 2 + 0) * 64 + lane];
                    bf16x8 k1 = kv[(bj * 2 + 1) * 64 + lane];
                    sa = __builtin_amdgcn_mfma_f32_16x16x32_bf16(qf0, k0, sa, 0, 0, 0);
                    sa = __builtin_amdgcn_mfma_f32_16x16x32_bf16(qf1, k1, sa, 0, 0, 0);
                    const float4 b4 = bias_sw[(i * 16 + jt0) * 64 + lane];
                    sa[0] = sa[0] * scale + b4.x;
                    sa[1] = sa[1] * scale + b4.y;
                    sa[2] = sa[2] * scale + b4.z;
                    sa[3] = sa[3] * scale + b4.w;
                    if (jt0 == i) {
                        #pragma unroll
                        for (int r = 0; r < 4; ++r)
                            if (l15 > quad * 4 + r) sa[r] = -1e30f;
                    }
                }
                if (jt1 < J) {
                    sb = zero4;
                    const size_t bj = (size_t)b * 16 + jt1;
                    bf16x8 k0 = kv[(bj * 2 + 0) * 64 + lane];
                    bf16x8 k1 = kv[(bj * 2 + 1) * 64 + lane];
                    sb = __builtin_amdgcn_mfma_f32_16x16x32_bf16(qf0, k0, sb, 0, 0, 0);
                    sb = __builtin_amdgcn_mfma_f32_16x16x32_bf16(qf1, k1, sb, 0, 0, 0);
                    const float4 b4 = bias_sw[(i * 16 + jt1) * 64 + lane];
                    sb[0] = sb[0] * scale + b4.x;
                    sb[1] = sb[1] * scale + b4.y;
                    sb[2] = sb[2] * scale + b4.z;
                    sb[3] = sb[3] * scale + b4.w;
                    if (jt1 == i) {
                        #pragma unroll
                        for (int r = 0; r < 4; ++r)
                            if (l15 > quad * 4 + r) sb[r] = -1e30f;
                    }
                } else {
                    sb[0] = -1e30f; sb[1] = -1e30f; sb[2] = -1e30f; sb[3] = -1e30f;
                }
                // ---- pair row max (16-lane group shares rows) ----
                float t4[4];
                #pragma unroll
                for (int r = 0; r < 4; ++r) t4[r] = fmaxf(sa[r], sb[r]);
                #pragma unroll
                for (int d = 1; d < 16; d <<= 1) {
                    #pragma unroll
                    for (int r = 0; r < 4; ++r) t4[r] = fmaxf(t4[r], __shfl_xor(t4[r], d, 64));
                }
                // ---- online rescale ----
                float al[4];
                #pragma unroll
                for (int r = 0; r < 4; ++r) {
                    float mn = fmaxf(m4[r], t4[r]);
                    al[r] = __expf(m4[r] - mn);   // first pair: exp(-huge)=0
                    m4[r] = mn;
                    l4[r] *= al[r];
                }
                #pragma unroll
                for (int n = 0; n < 4; ++n)
                #pragma unroll
                for (int r = 0; r < 4; ++r) o[n][r] *= al[r];
                // ---- exp + P -> per-wave LDS ----
                #pragma unroll
                for (int r = 0; r < 4; ++r) {
                    float e0 = __expf(sa[r] - m4[r]);
                    float e1 = __expf(sb[r] - m4[r]);   // invalid tile -> exp(-huge)=0
                    l4[r] += e0 + e1;                   // per-lane partial, reduced later
                    Pw[(quad * 4 + r) * PP + l15]      = f2bf(e0);
                    Pw[(quad * 4 + r) * PP + 16 + l15] = f2bf(e1);
                }
                // ---- PV ----
                bf16x8 pa = *(const bf16x8*)&Pw[l15 * PP + quad * 8];
                #pragma unroll
                for (int n = 0; n < 4; ++n) {
                    bf16x8 bv = *(const bf16x8*)&lds[(n * 16 + l15) * VP + p * 32 + quad * 8];
                    o[n] = __builtin_amdgcn_mfma_f32_16x16x32_bf16(pa, bv, o[n], 0, 0, 0);
                }
            }
        }
        // ---- row-sum reduce + normalize + store ----
        #pragma unroll
        for (int d = 1; d < 16; d <<= 1) {
            #pragma unroll
            for (int r = 0; r < 4; ++r) l4[r] += __shfl_xor(l4[r], d, 64);
        }
        float rl4[4];
        #pragma unroll
        for (int r = 0; r < 4; ++r) rl4[r] = 1.f / l4[r];
        float* ob = out + ((size_t)b * TT + t0) * HH;
        #pragma unroll
        for (int n = 0; n < 4; ++n)
        #pragma unroll
        for (int r = 0; r < 4; ++r)
            ob[(quad * 4 + r) * HH + n * 16 + l15] = o[n][r] * rl4[r];
    }
}

extern "C" void kernel_launch(void* const* d_in, const int* in_sizes, int n_in,
                              void* d_out, int out_size, void* d_ws, size_t ws_size,
                              hipStream_t stream) {
    const float* x  = (const float*)d_in[0];
    const float* Wk = (const float*)d_in[1];
    const float* Wq = (const float*)d_in[2];
    const float* Wv = (const float*)d_in[3];
    const float* pe = (const float*)d_in[4];
    float* out = (float*)d_out;

    // ws: poskT[16384]f | posqT[16384]f | bias_sw[16384]float4-elems(f) | W_sw[36864]u16
    //     | q_sw | k_sw | vg   (bf16, 16 MB each)  == 50,798,592 B total (same as r5)
    float*  poskT  = (float*)d_ws;
    float*  posqT  = poskT + TT * HH;
    float4* biassw = (float4*)(posqT + TT * HH);
    u16*    W_sw   = (u16*)((float*)biassw + TT * TT);
    u16*    q_sw   = W_sw + 3 * HH * CC;
    u16*    k_sw   = q_sw + (size_t)BB * TT * HH;
    u16*    vg     = k_sw + (size_t)BB * TT * HH;

    wprep_kernel<<<18, 256, 0, stream>>>(Wq, Wk, Wv, W_sw);
    pos_kernel<<<TT / 4, 256, 0, stream>>>(Wk, Wq, pe, poskT, posqT);
    bias_kernel<<<256, 64, 0, stream>>>(poskT, posqT, biassw);
    qkv_kernel<<<4 * BB, 256, 0, stream>>>(x, W_sw, q_sw, k_sw, vg);
    attn_kernel<<<2 * BB, 256, 0, stream>>>(q_sw, k_sw, vg, biassw, out);
}